// Round 6
// baseline (199.333 us; speedup 1.0000x reference)
//
#include <hip/hip_runtime.h>

// out[i] = sum_{j=0..9} in[10*i + j] * (j+1)/55   (stride==d==10 -> windows tile T exactly)
//
// R6 = R1 structure (best so far: 2 windows = 5 x float4 per thread, 80B lane stride)
//      + nontemporal loads/stores (streaming data, read-once: skip cache-fill policy)
//      + exact-cover grid: 7,680,000 threads = 30,000 blocks x 256 (no loop, no tail)

typedef float floatx4 __attribute__((ext_vector_type(4)));
typedef float floatx2 __attribute__((ext_vector_type(2)));

__global__ __launch_bounds__(256) void ts_decaylinear_kernel(
    const floatx4* __restrict__ in4, floatx2* __restrict__ out2) {

    const float w0 = 1.0f / 55.0f, w1 = 2.0f / 55.0f, w2 = 3.0f / 55.0f,
                w3 = 4.0f / 55.0f, w4 = 5.0f / 55.0f, w5 = 6.0f / 55.0f,
                w6 = 7.0f / 55.0f, w7 = 8.0f / 55.0f, w8 = 9.0f / 55.0f,
                w9 = 10.0f / 55.0f;

    const long long idx = (long long)blockIdx.x * blockDim.x + threadIdx.x;
    const floatx4* __restrict__ p = in4 + idx * 5;

    floatx4 a0 = __builtin_nontemporal_load(p + 0);
    floatx4 a1 = __builtin_nontemporal_load(p + 1);
    floatx4 a2 = __builtin_nontemporal_load(p + 2);
    floatx4 a3 = __builtin_nontemporal_load(p + 3);
    floatx4 a4 = __builtin_nontemporal_load(p + 4);

    float s0 = a0.x * w0 + a0.y * w1 + a0.z * w2 + a0.w * w3
             + a1.x * w4 + a1.y * w5 + a1.z * w6 + a1.w * w7
             + a2.x * w8 + a2.y * w9;

    float s1 = a2.z * w0 + a2.w * w1
             + a3.x * w2 + a3.y * w3 + a3.z * w4 + a3.w * w5
             + a4.x * w6 + a4.y * w7 + a4.z * w8 + a4.w * w9;

    floatx2 r;
    r.x = s0;
    r.y = s1;
    __builtin_nontemporal_store(r, &out2[idx]);
}

extern "C" void kernel_launch(void* const* d_in, const int* in_sizes, int n_in,
                              void* d_out, int out_size, void* d_ws, size_t ws_size,
                              hipStream_t stream) {
    const floatx4* in4 = (const floatx4*)d_in[0];
    floatx2* out2 = (floatx2*)d_out;

    // out_size = 15,360,000 ; one thread per PAIR of windows -> 7,680,000 threads
    long long n_pairs = (long long)out_size / 2;
    int grid = (int)((n_pairs + 255) / 256);  // = 30,000 exact

    ts_decaylinear_kernel<<<grid, 256, 0, stream>>>(in4, out2);
}

// Round 7
// 130.642 us; speedup vs baseline: 1.5258x; 1.5258x over previous
//
#include <hip/hip_runtime.h>

// out[i] = sum_{j=0..9} in[10*i + j] * (j+1)/55   (stride==d==10 -> windows tile T exactly)
//
// R7 = R1 (best: 134.7us) with ONE change: nontemporal STORE for the output
// (keep cached loads -- R6 proved NT loads catastrophic). Write stream no longer
// allocates in L2/L3, freeing fill/evict capacity for the 614MB read stream.

typedef float floatx2 __attribute__((ext_vector_type(2)));

__global__ __launch_bounds__(256) void ts_decaylinear_kernel(
    const float* __restrict__ in, floatx2* __restrict__ out2, long long n_pairs) {

    const float w0 = 1.0f / 55.0f, w1 = 2.0f / 55.0f, w2 = 3.0f / 55.0f,
                w3 = 4.0f / 55.0f, w4 = 5.0f / 55.0f, w5 = 6.0f / 55.0f,
                w6 = 7.0f / 55.0f, w7 = 8.0f / 55.0f, w8 = 9.0f / 55.0f,
                w9 = 10.0f / 55.0f;

    long long idx = (long long)blockIdx.x * blockDim.x + threadIdx.x;
    long long gs  = (long long)gridDim.x * blockDim.x;

    for (; idx < n_pairs; idx += gs) {
        const float4* p = reinterpret_cast<const float4*>(in) + idx * 5;
        float4 a0 = p[0];
        float4 a1 = p[1];
        float4 a2 = p[2];
        float4 a3 = p[3];
        float4 a4 = p[4];

        float s0 = a0.x * w0 + a0.y * w1 + a0.z * w2 + a0.w * w3
                 + a1.x * w4 + a1.y * w5 + a1.z * w6 + a1.w * w7
                 + a2.x * w8 + a2.y * w9;

        float s1 = a2.z * w0 + a2.w * w1
                 + a3.x * w2 + a3.y * w3 + a3.z * w4 + a3.w * w5
                 + a4.x * w6 + a4.y * w7 + a4.z * w8 + a4.w * w9;

        floatx2 r;
        r.x = s0;
        r.y = s1;
        __builtin_nontemporal_store(r, &out2[idx]);
    }
}

extern "C" void kernel_launch(void* const* d_in, const int* in_sizes, int n_in,
                              void* d_out, int out_size, void* d_ws, size_t ws_size,
                              hipStream_t stream) {
    const float* in = (const float*)d_in[0];
    floatx2* out2 = (floatx2*)d_out;

    long long n_pairs = (long long)out_size / 2;  // 7,680,000

    int block = 256;
    long long blocks_needed = (n_pairs + block - 1) / block;
    int grid = (int)(blocks_needed < 2048 ? blocks_needed : 2048);

    ts_decaylinear_kernel<<<grid, block, 0, stream>>>(in, out2, n_pairs);
}

// Round 8
// 130.557 us; speedup vs baseline: 1.5268x; 1.0007x over previous
//
#include <hip/hip_runtime.h>

// out[i] = sum_{j=0..9} in[10*i + j] * (j+1)/55   (stride==d==10 -> windows tile T exactly)
//
// R8 = R7 (best: 130.6us) + x2 manual unroll of the grid-stride loop:
// two gs-spaced pairs per iteration -> 10 independent float4 loads in flight
// (80B lane stride preserved -- the proven-good shape), NT float2 stores.

typedef float floatx2 __attribute__((ext_vector_type(2)));

__device__ __forceinline__ void win2(const float4* __restrict__ p, floatx2& r) {
    const float w0 = 1.0f / 55.0f, w1 = 2.0f / 55.0f, w2 = 3.0f / 55.0f,
                w3 = 4.0f / 55.0f, w4 = 5.0f / 55.0f, w5 = 6.0f / 55.0f,
                w6 = 7.0f / 55.0f, w7 = 8.0f / 55.0f, w8 = 9.0f / 55.0f,
                w9 = 10.0f / 55.0f;
    float4 a0 = p[0], a1 = p[1], a2 = p[2], a3 = p[3], a4 = p[4];
    r.x = a0.x * w0 + a0.y * w1 + a0.z * w2 + a0.w * w3
        + a1.x * w4 + a1.y * w5 + a1.z * w6 + a1.w * w7
        + a2.x * w8 + a2.y * w9;
    r.y = a2.z * w0 + a2.w * w1
        + a3.x * w2 + a3.y * w3 + a3.z * w4 + a3.w * w5
        + a4.x * w6 + a4.y * w7 + a4.z * w8 + a4.w * w9;
}

__global__ __launch_bounds__(256) void ts_decaylinear_kernel(
    const float* __restrict__ in, floatx2* __restrict__ out2, long long n_pairs) {

    long long idx = (long long)blockIdx.x * blockDim.x + threadIdx.x;
    const long long gs = (long long)gridDim.x * blockDim.x;
    const float4* base = reinterpret_cast<const float4*>(in);

    for (; idx < n_pairs; idx += 2 * gs) {
        const long long idx2 = idx + gs;
        floatx2 r0, r1;
        if (idx2 < n_pairs) {
            // issue both 5-load groups back-to-back (10 loads in flight)
            win2(base + idx * 5, r0);
            win2(base + idx2 * 5, r1);
            __builtin_nontemporal_store(r0, &out2[idx]);
            __builtin_nontemporal_store(r1, &out2[idx2]);
        } else {
            win2(base + idx * 5, r0);
            __builtin_nontemporal_store(r0, &out2[idx]);
        }
    }
}

extern "C" void kernel_launch(void* const* d_in, const int* in_sizes, int n_in,
                              void* d_out, int out_size, void* d_ws, size_t ws_size,
                              hipStream_t stream) {
    const float* in = (const float*)d_in[0];
    floatx2* out2 = (floatx2*)d_out;

    long long n_pairs = (long long)out_size / 2;  // 7,680,000

    int block = 256;
    long long blocks_needed = (n_pairs + block - 1) / block;
    int grid = (int)(blocks_needed < 2048 ? blocks_needed : 2048);

    ts_decaylinear_kernel<<<grid, block, 0, stream>>>(in, out2, n_pairs);
}